// Round 4
// baseline (3215.720 us; speedup 1.0000x reference)
//
#include <hip/hip_runtime.h>
#include <hip/hip_bf16.h>
#include <math.h>

// R4: fix R3 spill regression + keep weights L2-resident.
// - __launch_bounds__(512,2): VGPR cap 256 (compiler ~128), no spills,
//   registers available for deep B-load pipelining. 2 blocks/CU via LDS.
// - Non-temporal x loads (float4) and out stores: streaming data stops
//   evicting the 2.9 MB weight-fragment set from L2 -> B loads are L2 hits.

#define LSEQ 17
#define RS 260   // R row stride (f32)
#define TS 264   // T0/T1 row stride (u16)
#define SS 520   // S0 row stride (u16)
#define NTHR 512

typedef unsigned short u16;
typedef __attribute__((ext_vector_type(8))) short short8;
typedef __attribute__((ext_vector_type(4))) float f32x4;

__device__ __forceinline__ float b2f(u16 u) {
    union { unsigned int i; float f; } x; x.i = ((unsigned int)u) << 16; return x.f;
}
__device__ __forceinline__ u16 f2b(float f) {
    union { float f; unsigned int i; } x; x.f = f;
    unsigned int r = x.i + 0x7FFFu + ((x.i >> 16) & 1u);
    return (u16)(r >> 16);
}
__device__ __forceinline__ float gelu_t(float x) {
    float u = 1.5957691216057308f * (x + 0.044715f * x * x * x);
    return x / (1.0f + __expf(-u));
}
__device__ __forceinline__ float siluf(float x) { return x / (1.0f + __expf(-x)); }
__device__ __forceinline__ float softplusf(float x) {
    return (x > 20.0f) ? x : __logf(1.0f + __expf(x));
}

__device__ const int   ADJ_MASK[17] = {0x93,0x7,0xE,0xC,0x31,0x70,0x60,0x181,0x4B80,
                                       0x700,0x600,0x1900,0x3800,0x3000,0xC100,0x1C000,0x18000};
__device__ const float DEG[17]    = {4,3,3,2,3,3,2,3,5,3,2,3,3,2,3,3,2};
__device__ const int   HOPA[17]   = {0,1,4,7,2,5,8,3,6,9,11,14,10,12,15,13,16};
__device__ const int   GRAPHA[17] = {0,1,4,7,2,5,8,3,6,9,12,10,13,15,11,14,16};
__device__ const int   BPEI[17]   = {0,1,2,0,1,2,0,1,2,0,3,4,0,3,4,3,4};

// ws fragment offsets (elements, bf16)
#define OFF_GCN_W1   0
#define OFF_GCN_W2   131072
#define OFF_INPROJ   262144
#define OFF_OUTPROJ  524288
#define OFF_QKV      655360
#define OFF_ATTNPROJ 851968
#define OFF_MLP_W1   917504
#define OFF_MLP_W2   1179648
#define OFF_XPROJ    1441792

struct Params {
    const float *x, *gcn_ln_g, *gcn_ln_b, *gcn_w1, *gcn_b1, *gcn_w2, *gcn_b2,
                *bp_embed, *ssm_ln_g, *ssm_ln_b, *in_proj_w, *conv_w, *conv_b,
                *x_proj_w, *dt_proj_w, *dt_proj_b, *A_log, *Dp, *out_proj_w,
                *ln1_g, *ln1_b, *qkv_w, *attn_proj_w, *attn_proj_b,
                *ln2_g, *ln2_b, *mlp_w1, *mlp_b1, *mlp_w2, *mlp_b2;
    const u16* wws;
    float* out;
};

// ---------------- weight prepack: fp32 [K][N] -> bf16 B-fragments ----------------
// ws[off + ((kc*NT + nt)*64 + lane)*8 + j] = bf16(W[kc*32 + (lane>>4)*8 + j][nt*16 + (lane&15)])
__global__ __launch_bounds__(256) void prepack(Params P) {
    const int gid = blockIdx.x * 256 + threadIdx.x;
    const int cnt[9]  = {16384,16384,32768,16384,24576,8192,32768,32768,2048};
    const int Ns [9]  = {512,256,1024,256,768,256,1024,256,24};
    const int NPs[9]  = {512,256,1024,256,768,256,1024,256,32};
    const int offs[9] = {OFF_GCN_W1,OFF_GCN_W2,OFF_INPROJ,OFF_OUTPROJ,OFF_QKV,
                         OFF_ATTNPROJ,OFF_MLP_W1,OFF_MLP_W2,OFF_XPROJ};
    int e = 0, base = 0;
    while (e < 9 && gid >= base + cnt[e]) { base += cnt[e]; ++e; }
    if (e >= 9) return;
    const float* W;
    switch (e) {
        case 0: W = P.gcn_w1; break;      case 1: W = P.gcn_w2; break;
        case 2: W = P.in_proj_w; break;   case 3: W = P.out_proj_w; break;
        case 4: W = P.qkv_w; break;       case 5: W = P.attn_proj_w; break;
        case 6: W = P.mlp_w1; break;      case 7: W = P.mlp_w2; break;
        default: W = P.x_proj_w; break;
    }
    const int local = gid - base;
    const int lane = local & 63, frag = local >> 6;
    const int NT = NPs[e] >> 4;
    const int nt = frag % NT, kc = frag / NT;
    const int n = nt * 16 + (lane & 15);
    const int kbase = kc * 32 + (lane >> 4) * 8;
    u16 v[8];
    #pragma unroll
    for (int j = 0; j < 8; ++j)
        v[j] = (n < Ns[e]) ? f2b(W[(size_t)(kbase + j) * Ns[e] + n]) : (u16)0;
    u16* dst = (u16*)P.wws + offs[e] + ((size_t)frag * 64 + lane) * 8;
    *(short8*)dst = *(short8*)v;
}

// ---------------- MFMA helpers (8 waves: tiles ntl = wv + 8*i) ----------------
template <int KT, int NT4>
__device__ __forceinline__ void mfmaAcc(f32x4 acc[2][NT4],
        const u16* __restrict__ act, int ldin,
        const u16* __restrict__ wbase, int NT, int nt0, int ntcnt, int kc0) {
    const int lane = threadIdx.x & 63, wv = threadIdx.x >> 6;
    const int m = lane & 15, quad = lane >> 4;
    for (int kc = 0; kc < KT; ++kc) {
        short8 a0 = *(const short8*)(act + m * ldin + kc * 32 + quad * 8);
        short8 a1 = {0,0,0,0,0,0,0,0};
        if (m == 0) a1 = *(const short8*)(act + 16 * ldin + kc * 32 + quad * 8);
        #pragma unroll
        for (int i = 0; i < NT4; ++i) {
            const int ntl = wv + 8 * i;
            if (ntl < ntcnt) {
                const short8 b = *(const short8*)(wbase +
                    ((size_t)((kc0 + kc) * NT + nt0 + ntl) * 64 + lane) * 8);
                acc[0][i] = __builtin_amdgcn_mfma_f32_16x16x32_bf16(a0, b, acc[0][i], 0, 0, 0);
                acc[1][i] = __builtin_amdgcn_mfma_f32_16x16x32_bf16(a1, b, acc[1][i], 0, 0, 0);
            }
        }
    }
}

template <int NT4, class Epi>
__device__ __forceinline__ void mfmaStore(f32x4 acc[2][NT4], int ntcnt, Epi epi) {
    const int lane = threadIdx.x & 63, wv = threadIdx.x >> 6;
    const int col0 = lane & 15, quad = lane >> 4;
    #pragma unroll
    for (int i = 0; i < NT4; ++i) {
        const int ntl = wv + 8 * i;
        if (ntl < ntcnt) {
            const int cb = ntl * 16 + col0;
            #pragma unroll
            for (int r = 0; r < 4; ++r) epi(quad * 4 + r, cb, acc[0][i][r]);
            if (quad == 0) epi(16, cb, acc[1][i][0]);
        }
    }
}

template <int KT, int NT4, class Epi>
__device__ __forceinline__ void gemmM(const u16* act, int ldin,
        const u16* wbase, int NT, int nt0, int ntcnt, Epi epi) {
    f32x4 acc[2][NT4];
    #pragma unroll
    for (int mt = 0; mt < 2; ++mt)
        #pragma unroll
        for (int i = 0; i < NT4; ++i) acc[mt][i] = (f32x4){0.f,0.f,0.f,0.f};
    mfmaAcc<KT, NT4>(acc, act, ldin, wbase, NT, nt0, ntcnt, 0);
    mfmaStore<NT4>(acc, ntcnt, epi);
}

// ---------------- main fused kernel ----------------
__global__ __launch_bounds__(NTHR, 2) void fused_block(Params P) {
    __shared__ __align__(16) float R [LSEQ * RS];   // residual, fp32
    __shared__ __align__(16) u16   T0[LSEQ * TS];
    __shared__ __align__(16) u16   T1[LSEQ * TS];
    __shared__ __align__(16) u16   S0[LSEQ * SS];
    __shared__ __align__(16) u16   SC[8 * 17 * 17]; // attention scores
    __shared__ float Dbl[LSEQ * 24];
    __shared__ float Ah[289];

    const int tid = threadIdx.x;
    const int lane = tid & 63, wv = tid >> 6;
    const int b = blockIdx.x;
    const float* __restrict__ xg = P.x + (size_t)b * (LSEQ * 256);
    const u16* __restrict__ ws = P.wws;

    // x -> R via non-temporal float4 (don't evict weights from L2)
    for (int i4 = tid; i4 < LSEQ * 64; i4 += NTHR) {
        int l = i4 >> 6, d4 = (i4 & 63) * 4;
        f32x4 v = __builtin_nontemporal_load((const f32x4*)(xg + l * 256 + d4));
        *(f32x4*)(R + l * RS + d4) = v;
    }
    for (int i = tid; i < 289; i += NTHR) {
        int r = i / 17, c = i - r * 17;
        Ah[i] = ((ADJ_MASK[r] >> c) & 1) ? rsqrtf(DEG[r] * DEG[c]) : 0.f;
    }
    __syncthreads();

    auto ln17g = [&](auto ld, u16* dst, const float* g, const float* bb) {
        for (int l = wv; l < LSEQ; l += 8) {
            float v[4], s = 0.f, s2 = 0.f;
            #pragma unroll
            for (int j = 0; j < 4; ++j) {
                v[j] = ld(l, lane + 64 * j);
                s += v[j]; s2 += v[j] * v[j];
            }
            #pragma unroll
            for (int m = 1; m < 64; m <<= 1) {
                s  += __shfl_xor(s, m, 64);
                s2 += __shfl_xor(s2, m, 64);
            }
            float mean = s * (1.0f / 256.0f);
            float var  = s2 * (1.0f / 256.0f) - mean * mean;
            float rstd = rsqrtf(var + 1e-5f);
            #pragma unroll
            for (int j = 0; j < 4; ++j) {
                int d = lane + 64 * j;
                dst[l * TS + d] = f2b((v[j] - mean) * rstd * g[d] + bb[d]);
            }
        }
    };
    auto gconvIP = [&](u16* buf, int stride, int width) {
        for (int d = tid; d < width; d += NTHR) {
            float col[17];
            #pragma unroll
            for (int j = 0; j < 17; ++j) col[j] = b2f(buf[j * stride + d]);
            #pragma unroll
            for (int i = 0; i < 17; ++i) {
                float s = 0.f;
                #pragma unroll
                for (int j = 0; j < 17; ++j) s += Ah[i * 17 + j] * col[j];
                buf[i * stride + d] = f2b(s);
            }
        }
    };

    // ---------------- GCN ----------------
    ln17g([&](int l, int d) { return R[l * RS + d]; }, T0, P.gcn_ln_g, P.gcn_ln_b);
    __syncthreads();
    gconvIP(T0, TS, 256);
    __syncthreads();
    gemmM<8, 4>(T0, TS, ws + OFF_GCN_W1, 32, 0, 32,
        [&](int l, int c, float v) { S0[l * SS + c] = f2b(gelu_t(v + P.gcn_b1[c])); });
    __syncthreads();
    gconvIP(S0, SS, 512);
    __syncthreads();
    gemmM<16, 2>(S0, SS, ws + OFF_GCN_W2, 16, 0, 16,
        [&](int l, int c, float v) { R[l * RS + c] += v + P.gcn_b2[c]; });  // x_a
    __syncthreads();

    // ---------------- Mamba ----------------
    for (int i = tid; i < LSEQ * 256; i += NTHR) {
        int l = i >> 8, d = i & 255;
        T0[l * TS + d] = f2b(R[HOPA[l] * RS + d] + P.bp_embed[BPEI[l] * 256 + d]);
    }
    __syncthreads();
    ln17g([&](int l, int d) { return b2f(T0[l * TS + d]); }, T1, P.ssm_ln_g, P.ssm_ln_b);
    __syncthreads();
    // xm = silu(conv(in_proj[:, :512]))
    gemmM<8, 4>(T1, TS, ws + OFF_INPROJ, 64, 0, 32,
        [&](int l, int c, float v) { S0[l * SS + c] = f2b(siluf(v * P.conv_w[c] + P.conv_b[c])); });
    __syncthreads();
    // x_proj (N=24 padded to 32): tiles 0,1 -> waves 0,1
    gemmM<16, 1>(S0, SS, ws + OFF_XPROJ, 2, 0, 2,
        [&](int l, int c, float v) { if (c < 24) Dbl[l * 24 + c] = v; });
    __syncthreads();
    // selective scan: one channel per thread
    {
        const int d = tid;
        float wdt[16];
        #pragma unroll
        for (int r = 0; r < 16; ++r) wdt[r] = P.dt_proj_w[r * 512 + d];
        const float dtb = P.dt_proj_b[d];
        float Ar[4];
        #pragma unroll
        for (int s = 0; s < 4; ++s) Ar[s] = -__expf(P.A_log[d * 4 + s]);
        const float Dpd = P.Dp[d];
        float h0 = 0.f, h1 = 0.f, h2 = 0.f, h3 = 0.f;
        for (int t = 0; t < LSEQ; ++t) {
            float a = dtb;
            #pragma unroll
            for (int r = 0; r < 16; ++r) a += Dbl[t * 24 + r] * wdt[r];
            float dt = softplusf(a);
            float xm = b2f(S0[t * SS + d]);
            float dtxm = dt * xm;
            h0 = __expf(dt * Ar[0]) * h0 + dtxm * Dbl[t * 24 + 16];
            h1 = __expf(dt * Ar[1]) * h1 + dtxm * Dbl[t * 24 + 17];
            h2 = __expf(dt * Ar[2]) * h2 + dtxm * Dbl[t * 24 + 18];
            h3 = __expf(dt * Ar[3]) * h3 + dtxm * Dbl[t * 24 + 19];
            float y = h0 * Dbl[t * 24 + 20] + h1 * Dbl[t * 24 + 21]
                    + h2 * Dbl[t * 24 + 22] + h3 * Dbl[t * 24 + 23];
            y += Dpd * xm;
            S0[t * SS + d] = f2b(y);
        }
    }
    __syncthreads();
    // z half of in_proj; gate y in place
    gemmM<8, 4>(T1, TS, ws + OFF_INPROJ, 64, 32, 32,
        [&](int l, int c, float v) {
            float y = b2f(S0[l * SS + c]);
            S0[l * SS + c] = f2b(y * siluf(v));
        });
    __syncthreads();
    gemmM<16, 2>(S0, SS, ws + OFF_OUTPROJ, 16, 0, 16,
        [&](int l, int c, float v) { T0[l * TS + c] = f2b(v); });
    __syncthreads();
    // x_b = 2*x_a + scatter(mamba_out)
    for (int i = tid; i < LSEQ * 256; i += NTHR) {
        int l = i >> 8, d = i & 255;
        R[l * RS + d] = 2.0f * R[l * RS + d] + b2f(T0[GRAPHA[l] * TS + d]);
    }
    __syncthreads();

    // ---------------- Attention ----------------
    ln17g([&](int l, int d) { return R[l * RS + d]; }, T0, P.ln1_g, P.ln1_b);
    __syncthreads();
    // fused QKV: c<256 -> Q (T1); c in [256,768) -> K|V (S0 cols c-256)
    gemmM<8, 6>(T0, TS, ws + OFF_QKV, 48, 0, 48,
        [&](int l, int c, float v) {
            if (c < 256) T1[l * TS + c] = f2b(v);
            else         S0[l * SS + (c - 256)] = f2b(v);
        });
    __syncthreads();
    {
        const int h = tid >> 6, p = tid & 63;  // 8 heads x 64 threads
        for (int idx = p; idx < 289; idx += 64) {
            int i = idx / 17, j = idx - i * 17;
            float s = 0.f;
            #pragma unroll
            for (int d2 = 0; d2 < 32; ++d2)
                s += b2f(T1[i * TS + h * 32 + d2]) * b2f(S0[j * SS + h * 32 + d2]);
            SC[(h * 17 + i) * 17 + j] = f2b(s * 0.17677669529663687f);
        }
    }
    __syncthreads();
    if (tid < 136) {
        u16* row = SC + tid * 17;
        float e[17], mx = -3.0e38f, sum = 0.f;
        #pragma unroll
        for (int j = 0; j < 17; ++j) mx = fmaxf(mx, b2f(row[j]));
        #pragma unroll
        for (int j = 0; j < 17; ++j) { e[j] = __expf(b2f(row[j]) - mx); sum += e[j]; }
        float inv = 1.0f / sum;
        #pragma unroll
        for (int j = 0; j < 17; ++j) row[j] = f2b(e[j] * inv);
    }
    __syncthreads();
    {
        const int h = tid >> 6, sub = (tid >> 5) & 1, dd = tid & 31;
        for (int i = sub; i < 17; i += 2) {
            float s = 0.f;
            #pragma unroll
            for (int j = 0; j < 17; ++j)
                s += b2f(SC[(h * 17 + i) * 17 + j]) * b2f(S0[j * SS + 256 + h * 32 + dd]);
            T0[i * TS + h * 32 + dd] = f2b(s);  // o (ln1 out is dead)
        }
    }
    __syncthreads();
    // o' = attn_proj(o) + bias
    gemmM<8, 2>(T0, TS, ws + OFF_ATTNPROJ, 16, 0, 16,
        [&](int l, int c, float v) { T1[l * TS + c] = f2b(v + P.attn_proj_b[c]); });
    __syncthreads();

    // ---------------- MLP + final ----------------
    ln17g([&](int l, int d) { return R[l * RS + d] + b2f(T1[l * TS + d]); },
          T0, P.ln2_g, P.ln2_b);
    __syncthreads();
    {
        f32x4 accO[2][2];
        #pragma unroll
        for (int mt = 0; mt < 2; ++mt)
            #pragma unroll
            for (int i = 0; i < 2; ++i) accO[mt][i] = (f32x4){0.f,0.f,0.f,0.f};
        #pragma unroll
        for (int half = 0; half < 2; ++half) {
            gemmM<8, 4>(T0, TS, ws + OFF_MLP_W1, 64, half * 32, 32,
                [&](int l, int c, float v) {
                    S0[l * SS + c] = f2b(gelu_t(v + P.mlp_b1[half * 512 + c]));
                });
            __syncthreads();
            mfmaAcc<16, 2>(accO, S0, SS, ws + OFF_MLP_W2, 16, 0, 16, half * 16);
            __syncthreads();  // S0 reused next half
        }
        float* outg = P.out + (size_t)b * (LSEQ * 256);
        mfmaStore<2>(accO, 16, [&](int l, int c, float v) {
            float r = v + P.mlp_b2[c] + 2.0f * R[l * RS + c] + b2f(T1[l * TS + c]);
            __builtin_nontemporal_store(r, outg + l * 256 + c);
        });
    }
}

extern "C" void kernel_launch(void* const* d_in, const int* in_sizes, int n_in,
                              void* d_out, int out_size, void* d_ws, size_t ws_size,
                              hipStream_t stream) {
    (void)in_sizes; (void)n_in; (void)ws_size; (void)out_size;
    Params P;
    P.x           = (const float*)d_in[0];
    P.gcn_ln_g    = (const float*)d_in[1];
    P.gcn_ln_b    = (const float*)d_in[2];
    P.gcn_w1      = (const float*)d_in[3];
    P.gcn_b1      = (const float*)d_in[4];
    P.gcn_w2      = (const float*)d_in[5];
    P.gcn_b2      = (const float*)d_in[6];
    P.bp_embed    = (const float*)d_in[7];
    P.ssm_ln_g    = (const float*)d_in[8];
    P.ssm_ln_b    = (const float*)d_in[9];
    P.in_proj_w   = (const float*)d_in[10];
    P.conv_w      = (const float*)d_in[11];
    P.conv_b      = (const float*)d_in[12];
    P.x_proj_w    = (const float*)d_in[13];
    P.dt_proj_w   = (const float*)d_in[14];
    P.dt_proj_b   = (const float*)d_in[15];
    P.A_log       = (const float*)d_in[16];
    P.Dp          = (const float*)d_in[17];
    P.out_proj_w  = (const float*)d_in[18];
    P.ln1_g       = (const float*)d_in[19];
    P.ln1_b       = (const float*)d_in[20];
    P.qkv_w       = (const float*)d_in[21];
    P.attn_proj_w = (const float*)d_in[22];
    P.attn_proj_b = (const float*)d_in[23];
    P.ln2_g       = (const float*)d_in[24];
    P.ln2_b       = (const float*)d_in[25];
    P.mlp_w1      = (const float*)d_in[26];
    P.mlp_b1      = (const float*)d_in[27];
    P.mlp_w2      = (const float*)d_in[28];
    P.mlp_b2      = (const float*)d_in[29];
    P.wws         = (const u16*)d_ws;
    P.out         = (float*)d_out;
    hipLaunchKernelGGL(prepack, dim3(712), dim3(256), 0, stream, P);
    hipLaunchKernelGGL(fused_block, dim3(4096), dim3(NTHR), 0, stream, P);
}

// Round 5
// 2277.149 us; speedup vs baseline: 1.4122x; 1.4122x over previous
//
#include <hip/hip_runtime.h>
#include <hip/hip_bf16.h>
#include <math.h>

// R5: 2 elements per block (grid 2048), 34-row packed activations -> 3 M-tiles.
// Halves per-element weight traffic, +33% MFMA/load ratio, 25% fewer MFMAs.
// Dynamic LDS 117.5 KB (1 block/CU), 512 thr, launch_bounds(512,1) => 256-reg
// budget, NT4<=4 => no scratch spills (WRITE_SIZE is the test).

#define LSEQ 17
#define RS 260   // R row stride (f32)
#define TS 264   // AC/T1 row stride (u16)
#define SS 520   // W5 row stride (u16)
#define NTHR 512

typedef unsigned short u16;
typedef __attribute__((ext_vector_type(8))) short short8;
typedef __attribute__((ext_vector_type(4))) float f32x4;

__device__ __forceinline__ float b2f(u16 u) {
    union { unsigned int i; float f; } x; x.i = ((unsigned int)u) << 16; return x.f;
}
__device__ __forceinline__ u16 f2b(float f) {
    union { float f; unsigned int i; } x; x.f = f;
    unsigned int r = x.i + 0x7FFFu + ((x.i >> 16) & 1u);
    return (u16)(r >> 16);
}
__device__ __forceinline__ float gelu_t(float x) {
    float u = 1.5957691216057308f * (x + 0.044715f * x * x * x);
    return x / (1.0f + __expf(-u));
}
__device__ __forceinline__ float siluf(float x) { return x / (1.0f + __expf(-x)); }
__device__ __forceinline__ float softplusf(float x) {
    return (x > 20.0f) ? x : __logf(1.0f + __expf(x));
}

__device__ const int   ADJ_MASK[17] = {0x93,0x7,0xE,0xC,0x31,0x70,0x60,0x181,0x4B80,
                                       0x700,0x600,0x1900,0x3800,0x3000,0xC100,0x1C000,0x18000};
__device__ const float DEG[17]    = {4,3,3,2,3,3,2,3,5,3,2,3,3,2,3,3,2};
__device__ const int   HOPA[17]   = {0,1,4,7,2,5,8,3,6,9,11,14,10,12,15,13,16};
__device__ const int   GRAPHA[17] = {0,1,4,7,2,5,8,3,6,9,12,10,13,15,11,14,16};
__device__ const int   BPEI[17]   = {0,1,2,0,1,2,0,1,2,0,3,4,0,3,4,3,4};

// ws fragment offsets (elements, bf16)
#define OFF_GCN_W1   0
#define OFF_GCN_W2   131072
#define OFF_INPROJ   262144
#define OFF_OUTPROJ  524288
#define OFF_QKV      655360
#define OFF_ATTNPROJ 851968
#define OFF_MLP_W1   917504
#define OFF_MLP_W2   1179648
#define OFF_XPROJ    1441792

// dynamic LDS carve (bytes)
#define SM_R    0
#define SM_AC   35360
#define SM_T1   53312
#define SM_W5   71264
#define SM_SC   106624
#define SM_DBL  115872
#define SM_AH   119136
#define SMEM_BYTES 120320

struct Params {
    const float *x, *gcn_ln_g, *gcn_ln_b, *gcn_w1, *gcn_b1, *gcn_w2, *gcn_b2,
                *bp_embed, *ssm_ln_g, *ssm_ln_b, *in_proj_w, *conv_w, *conv_b,
                *x_proj_w, *dt_proj_w, *dt_proj_b, *A_log, *Dp, *out_proj_w,
                *ln1_g, *ln1_b, *qkv_w, *attn_proj_w, *attn_proj_b,
                *ln2_g, *ln2_b, *mlp_w1, *mlp_b1, *mlp_w2, *mlp_b2;
    const u16* wws;
    float* out;
};

// ---------------- weight prepack: fp32 [K][N] -> bf16 B-fragments ----------------
__global__ __launch_bounds__(256) void prepack(Params P) {
    const int gid = blockIdx.x * 256 + threadIdx.x;
    const int cnt[9]  = {16384,16384,32768,16384,24576,8192,32768,32768,2048};
    const int Ns [9]  = {512,256,1024,256,768,256,1024,256,24};
    const int NPs[9]  = {512,256,1024,256,768,256,1024,256,32};
    const int offs[9] = {OFF_GCN_W1,OFF_GCN_W2,OFF_INPROJ,OFF_OUTPROJ,OFF_QKV,
                         OFF_ATTNPROJ,OFF_MLP_W1,OFF_MLP_W2,OFF_XPROJ};
    int e = 0, base = 0;
    while (e < 9 && gid >= base + cnt[e]) { base += cnt[e]; ++e; }
    if (e >= 9) return;
    const float* W;
    switch (e) {
        case 0: W = P.gcn_w1; break;      case 1: W = P.gcn_w2; break;
        case 2: W = P.in_proj_w; break;   case 3: W = P.out_proj_w; break;
        case 4: W = P.qkv_w; break;       case 5: W = P.attn_proj_w; break;
        case 6: W = P.mlp_w1; break;      case 7: W = P.mlp_w2; break;
        default: W = P.x_proj_w; break;
    }
    const int local = gid - base;
    const int lane = local & 63, frag = local >> 6;
    const int NT = NPs[e] >> 4;
    const int nt = frag % NT, kc = frag / NT;
    const int n = nt * 16 + (lane & 15);
    const int kbase = kc * 32 + (lane >> 4) * 8;
    u16 v[8];
    #pragma unroll
    for (int j = 0; j < 8; ++j)
        v[j] = (n < Ns[e]) ? f2b(W[(size_t)(kbase + j) * Ns[e] + n]) : (u16)0;
    u16* dst = (u16*)P.wws + offs[e] + ((size_t)frag * 64 + lane) * 8;
    *(short8*)dst = *(short8*)v;
}

// ---------------- MFMA helpers: 3 M-tiles over 34 packed rows ----------------
template <int KT, int NT4>
__device__ __forceinline__ void mfmaAcc(f32x4 acc[3][NT4],
        const u16* __restrict__ act, int ldin,
        const u16* __restrict__ wbase, int NT, int nt0, int ntcnt, int kc0) {
    const int lane = threadIdx.x & 63, wv = threadIdx.x >> 6;
    const int m = lane & 15, quad = lane >> 4;
    const bool v2 = (m < 2);
    for (int kc = 0; kc < KT; ++kc) {
        const int ko = kc * 32 + quad * 8;
        short8 a0 = *(const short8*)(act + m * ldin + ko);
        short8 a1 = *(const short8*)(act + (16 + m) * ldin + ko);
        short8 a2 = {0,0,0,0,0,0,0,0};
        if (v2) a2 = *(const short8*)(act + (32 + m) * ldin + ko);
        #pragma unroll
        for (int i = 0; i < NT4; ++i) {
            const int ntl = wv + 8 * i;
            if (ntl < ntcnt) {
                const short8 b = *(const short8*)(wbase +
                    ((size_t)((kc0 + kc) * NT + nt0 + ntl) * 64 + lane) * 8);
                acc[0][i] = __builtin_amdgcn_mfma_f32_16x16x32_bf16(a0, b, acc[0][i], 0, 0, 0);
                acc[1][i] = __builtin_amdgcn_mfma_f32_16x16x32_bf16(a1, b, acc[1][i], 0, 0, 0);
                acc[2][i] = __builtin_amdgcn_mfma_f32_16x16x32_bf16(a2, b, acc[2][i], 0, 0, 0);
            }
        }
    }
}

// epi(rr, c_rel, val): rr in [0,34) packed row, c_rel relative to nt0*16.
template <int NT4, class Epi>
__device__ __forceinline__ void mfmaStore(f32x4 acc[3][NT4], int ntcnt, Epi epi) {
    const int lane = threadIdx.x & 63, wv = threadIdx.x >> 6;
    const int col0 = lane & 15, quad = lane >> 4;
    #pragma unroll
    for (int i = 0; i < NT4; ++i) {
        const int ntl = wv + 8 * i;
        if (ntl < ntcnt) {
            const int cb = ntl * 16 + col0;
            #pragma unroll
            for (int r = 0; r < 4; ++r) epi(quad * 4 + r, cb, acc[0][i][r]);
            #pragma unroll
            for (int r = 0; r < 4; ++r) epi(16 + quad * 4 + r, cb, acc[1][i][r]);
            if (quad == 0) {
                epi(32, cb, acc[2][i][0]);
                epi(33, cb, acc[2][i][1]);
            }
        }
    }
}

template <int KT, int NT4, class Epi>
__device__ __forceinline__ void gemmM(const u16* act, int ldin,
        const u16* wbase, int NT, int nt0, int ntcnt, Epi epi) {
    f32x4 acc[3][NT4];
    #pragma unroll
    for (int mt = 0; mt < 3; ++mt)
        #pragma unroll
        for (int i = 0; i < NT4; ++i) acc[mt][i] = (f32x4){0.f,0.f,0.f,0.f};
    mfmaAcc<KT, NT4>(acc, act, ldin, wbase, NT, nt0, ntcnt, 0);
    mfmaStore<NT4>(acc, ntcnt, epi);
}

// ---------------- main fused kernel: 2 elements per block ----------------
__global__ __launch_bounds__(NTHR, 1) void fused_block(Params P) {
    extern __shared__ __align__(16) char smem[];
    float* R   = (float*)(smem + SM_R);    // [34][260] f32
    u16*   AC  = (u16*)  (smem + SM_AC);   // [34][264]
    u16*   T1  = (u16*)  (smem + SM_T1);   // [34][264]
    u16*   W5  = (u16*)  (smem + SM_W5);   // [34][520]
    u16*   SC  = (u16*)  (smem + SM_SC);   // [16][289]
    float* Dbl = (float*)(smem + SM_DBL);  // [34][24]
    float* Ah  = (float*)(smem + SM_AH);   // [289]

    const int tid = threadIdx.x;
    const int lane = tid & 63, wv = tid >> 6;
    const float* __restrict__ xg = P.x + (size_t)blockIdx.x * (2 * LSEQ * 256);
    const u16* __restrict__ ws = P.wws;

    // x -> R (34 contiguous rows), non-temporal float4
    for (int i4 = tid; i4 < 34 * 64; i4 += NTHR) {
        int rr = i4 >> 6, d4 = (i4 & 63) * 4;
        f32x4 v = __builtin_nontemporal_load((const f32x4*)(xg + rr * 256 + d4));
        *(f32x4*)(R + rr * RS + d4) = v;
    }
    for (int i = tid; i < 289; i += NTHR) {
        int r = i / 17, c = i - r * 17;
        Ah[i] = ((ADJ_MASK[r] >> c) & 1) ? rsqrtf(DEG[r] * DEG[c]) : 0.f;
    }
    __syncthreads();

    auto ln34 = [&](auto ld, u16* dst, const float* g, const float* bb) {
        for (int rr = wv; rr < 34; rr += 8) {
            float v[4], s = 0.f, s2 = 0.f;
            #pragma unroll
            for (int j = 0; j < 4; ++j) {
                v[j] = ld(rr, lane + 64 * j);
                s += v[j]; s2 += v[j] * v[j];
            }
            #pragma unroll
            for (int m = 1; m < 64; m <<= 1) {
                s  += __shfl_xor(s, m, 64);
                s2 += __shfl_xor(s2, m, 64);
            }
            float mean = s * (1.0f / 256.0f);
            float var  = s2 * (1.0f / 256.0f) - mean * mean;
            float rstd = rsqrtf(var + 1e-5f);
            #pragma unroll
            for (int j = 0; j < 4; ++j) {
                int d = lane + 64 * j;
                dst[rr * TS + d] = f2b((v[j] - mean) * rstd * g[d] + bb[d]);
            }
        }
    };
    // per-element graph conv, in place; width = 256 or 512
    auto gconvIP = [&](u16* buf, int stride, int width) {
        for (int u = tid; u < 2 * width; u += NTHR) {
            int e = u / width, d = u - e * width;
            u16* be = buf + e * LSEQ * stride;
            float col[17];
            #pragma unroll
            for (int j = 0; j < 17; ++j) col[j] = b2f(be[j * stride + d]);
            #pragma unroll
            for (int i = 0; i < 17; ++i) {
                float s = 0.f;
                #pragma unroll
                for (int j = 0; j < 17; ++j) s += Ah[i * 17 + j] * col[j];
                be[i * stride + d] = f2b(s);
            }
        }
    };

    // ---------------- GCN ----------------
    ln34([&](int rr, int d) { return R[rr * RS + d]; }, AC, P.gcn_ln_g, P.gcn_ln_b);
    __syncthreads();
    gconvIP(AC, TS, 256);
    __syncthreads();
    gemmM<8, 4>(AC, TS, ws + OFF_GCN_W1, 32, 0, 32,
        [&](int rr, int c, float v) { W5[rr * SS + c] = f2b(gelu_t(v + P.gcn_b1[c])); });
    __syncthreads();
    gconvIP(W5, SS, 512);
    __syncthreads();
    gemmM<16, 2>(W5, SS, ws + OFF_GCN_W2, 16, 0, 16,
        [&](int rr, int c, float v) { R[rr * RS + c] += v + P.gcn_b2[c]; });  // x_a
    __syncthreads();

    // ---------------- Mamba ----------------
    for (int i = tid; i < 34 * 256; i += NTHR) {
        int rr = i >> 8, d = i & 255;
        int e = (rr >= 17), l = rr - e * 17;
        AC[rr * TS + d] = f2b(R[(e * 17 + HOPA[l]) * RS + d] + P.bp_embed[BPEI[l] * 256 + d]);
    }
    __syncthreads();
    ln34([&](int rr, int d) { return b2f(AC[rr * TS + d]); }, T1, P.ssm_ln_g, P.ssm_ln_b);
    __syncthreads();
    // xm = silu(conv(in_proj[:, :512]))
    gemmM<8, 4>(T1, TS, ws + OFF_INPROJ, 64, 0, 32,
        [&](int rr, int c, float v) { W5[rr * SS + c] = f2b(siluf(v * P.conv_w[c] + P.conv_b[c])); });
    __syncthreads();
    // x_proj (N=24 padded to 32)
    gemmM<16, 1>(W5, SS, ws + OFF_XPROJ, 2, 0, 2,
        [&](int rr, int c, float v) { if (c < 24) Dbl[rr * 24 + c] = v; });
    __syncthreads();
    // selective scan: thread owns channel d for BOTH elements (2 indep chains)
    {
        const int d = tid;
        float wdt[16];
        #pragma unroll
        for (int r = 0; r < 16; ++r) wdt[r] = P.dt_proj_w[r * 512 + d];
        const float dtb = P.dt_proj_b[d];
        float Ar[4];
        #pragma unroll
        for (int s = 0; s < 4; ++s) Ar[s] = -__expf(P.A_log[d * 4 + s]);
        const float Dpd = P.Dp[d];
        float ha0 = 0.f, ha1 = 0.f, ha2 = 0.f, ha3 = 0.f;
        float hb0 = 0.f, hb1 = 0.f, hb2 = 0.f, hb3 = 0.f;
        for (int t = 0; t < LSEQ; ++t) {
            const float* Da = Dbl + t * 24;
            const float* Db = Dbl + (17 + t) * 24;
            float aa = dtb, ab = dtb;
            #pragma unroll
            for (int r = 0; r < 16; ++r) { aa += Da[r] * wdt[r]; ab += Db[r] * wdt[r]; }
            float dta = softplusf(aa), dtb2 = softplusf(ab);
            float xma = b2f(W5[t * SS + d]), xmb = b2f(W5[(17 + t) * SS + d]);
            float pa = dta * xma, pb = dtb2 * xmb;
            ha0 = __expf(dta * Ar[0]) * ha0 + pa * Da[16];
            ha1 = __expf(dta * Ar[1]) * ha1 + pa * Da[17];
            ha2 = __expf(dta * Ar[2]) * ha2 + pa * Da[18];
            ha3 = __expf(dta * Ar[3]) * ha3 + pa * Da[19];
            hb0 = __expf(dtb2 * Ar[0]) * hb0 + pb * Db[16];
            hb1 = __expf(dtb2 * Ar[1]) * hb1 + pb * Db[17];
            hb2 = __expf(dtb2 * Ar[2]) * hb2 + pb * Db[18];
            hb3 = __expf(dtb2 * Ar[3]) * hb3 + pb * Db[19];
            float ya = ha0 * Da[20] + ha1 * Da[21] + ha2 * Da[22] + ha3 * Da[23] + Dpd * xma;
            float yb = hb0 * Db[20] + hb1 * Db[21] + hb2 * Db[22] + hb3 * Db[23] + Dpd * xmb;
            W5[t * SS + d] = f2b(ya);
            W5[(17 + t) * SS + d] = f2b(yb);
        }
    }
    __syncthreads();
    // z half of in_proj; gate y in place
    gemmM<8, 4>(T1, TS, ws + OFF_INPROJ, 64, 32, 32,
        [&](int rr, int c, float v) {
            float y = b2f(W5[rr * SS + c]);
            W5[rr * SS + c] = f2b(y * siluf(v));
        });
    __syncthreads();
    gemmM<16, 2>(W5, SS, ws + OFF_OUTPROJ, 16, 0, 16,
        [&](int rr, int c, float v) { AC[rr * TS + c] = f2b(v); });
    __syncthreads();
    // x_b = 2*x_a + scatter(mamba_out)
    for (int i = tid; i < 34 * 256; i += NTHR) {
        int rr = i >> 8, d = i & 255;
        int e = (rr >= 17), l = rr - e * 17;
        R[rr * RS + d] = 2.0f * R[rr * RS + d] + b2f(AC[(e * 17 + GRAPHA[l]) * TS + d]);
    }
    __syncthreads();

    // ---------------- Attention ----------------
    ln34([&](int rr, int d) { return R[rr * RS + d]; }, AC, P.ln1_g, P.ln1_b);
    __syncthreads();
    // QKV in two passes (tiles 0-23, 24-47). abs col cc: <256 Q -> T1; else K|V -> W5
    gemmM<8, 3>(AC, TS, ws + OFF_QKV, 48, 0, 24,
        [&](int rr, int c, float v) {
            if (c < 256) T1[rr * TS + c] = f2b(v);
            else         W5[rr * SS + (c - 256)] = f2b(v);
        });
    gemmM<8, 3>(AC, TS, ws + OFF_QKV, 48, 24, 24,
        [&](int rr, int c, float v) {
            W5[rr * SS + (c + 128)] = f2b(v);  // cc = c+384 -> W5 col cc-256
        });
    __syncthreads();
    {
        const int unit = tid >> 5;             // (e,h): e = unit>>3, h = unit&7
        const int e = unit >> 3, h = unit & 7, p = tid & 31;
        const int rb = e * 17;
        for (int idx = p; idx < 289; idx += 32) {
            int i = idx / 17, j = idx - i * 17;
            float s = 0.f;
            #pragma unroll
            for (int d2 = 0; d2 < 32; ++d2)
                s += b2f(T1[(rb + i) * TS + h * 32 + d2]) * b2f(W5[(rb + j) * SS + h * 32 + d2]);
            SC[unit * 289 + i * 17 + j] = f2b(s * 0.17677669529663687f);
        }
    }
    __syncthreads();
    if (tid < 272) {
        u16* row = SC + tid * 17;
        float e[17], mx = -3.0e38f, sum = 0.f;
        #pragma unroll
        for (int j = 0; j < 17; ++j) mx = fmaxf(mx, b2f(row[j]));
        #pragma unroll
        for (int j = 0; j < 17; ++j) { e[j] = __expf(b2f(row[j]) - mx); sum += e[j]; }
        float inv = 1.0f / sum;
        #pragma unroll
        for (int j = 0; j < 17; ++j) row[j] = f2b(e[j] * inv);
    }
    __syncthreads();
    {
        const int unit = tid >> 5;
        const int e = unit >> 3, h = unit & 7, dd = tid & 31;
        const int rb = e * 17;
        for (int i = 0; i < 17; ++i) {
            float s = 0.f;
            #pragma unroll
            for (int j = 0; j < 17; ++j)
                s += b2f(SC[unit * 289 + i * 17 + j]) * b2f(W5[(rb + j) * SS + 256 + h * 32 + dd]);
            AC[(rb + i) * TS + h * 32 + dd] = f2b(s);  // o (ln1 out dead)
        }
    }
    __syncthreads();
    // o' = attn_proj(o) + bias
    gemmM<8, 2>(AC, TS, ws + OFF_ATTNPROJ, 16, 0, 16,
        [&](int rr, int c, float v) { T1[rr * TS + c] = f2b(v + P.attn_proj_b[c]); });
    __syncthreads();

    // ---------------- MLP + final ----------------
    ln34([&](int rr, int d) { return R[rr * RS + d] + b2f(T1[rr * TS + d]); },
         AC, P.ln2_g, P.ln2_b);
    __syncthreads();
    {
        f32x4 accO[3][2];
        #pragma unroll
        for (int mt = 0; mt < 3; ++mt)
            #pragma unroll
            for (int i = 0; i < 2; ++i) accO[mt][i] = (f32x4){0.f,0.f,0.f,0.f};
        #pragma unroll
        for (int half = 0; half < 2; ++half) {
            gemmM<8, 4>(AC, TS, ws + OFF_MLP_W1, 64, half * 32, 32,
                [&](int rr, int c, float v) {
                    W5[rr * SS + c] = f2b(gelu_t(v + P.mlp_b1[half * 512 + c]));
                });
            __syncthreads();
            mfmaAcc<16, 2>(accO, W5, SS, ws + OFF_MLP_W2, 16, 0, 16, half * 16);
            __syncthreads();  // W5 reused next half
        }
        float* outg = P.out + (size_t)blockIdx.x * (2 * LSEQ * 256);
        mfmaStore<2>(accO, 16, [&](int rr, int c, float v) {
            float r = v + P.mlp_b2[c] + 2.0f * R[rr * RS + c] + b2f(T1[rr * TS + c]);
            __builtin_nontemporal_store(r, outg + rr * 256 + c);
        });
    }
}

extern "C" void kernel_launch(void* const* d_in, const int* in_sizes, int n_in,
                              void* d_out, int out_size, void* d_ws, size_t ws_size,
                              hipStream_t stream) {
    (void)in_sizes; (void)n_in; (void)ws_size; (void)out_size;
    Params P;
    P.x           = (const float*)d_in[0];
    P.gcn_ln_g    = (const float*)d_in[1];
    P.gcn_ln_b    = (const float*)d_in[2];
    P.gcn_w1      = (const float*)d_in[3];
    P.gcn_b1      = (const float*)d_in[4];
    P.gcn_w2      = (const float*)d_in[5];
    P.gcn_b2      = (const float*)d_in[6];
    P.bp_embed    = (const float*)d_in[7];
    P.ssm_ln_g    = (const float*)d_in[8];
    P.ssm_ln_b    = (const float*)d_in[9];
    P.in_proj_w   = (const float*)d_in[10];
    P.conv_w      = (const float*)d_in[11];
    P.conv_b      = (const float*)d_in[12];
    P.x_proj_w    = (const float*)d_in[13];
    P.dt_proj_w   = (const float*)d_in[14];
    P.dt_proj_b   = (const float*)d_in[15];
    P.A_log       = (const float*)d_in[16];
    P.Dp          = (const float*)d_in[17];
    P.out_proj_w  = (const float*)d_in[18];
    P.ln1_g       = (const float*)d_in[19];
    P.ln1_b       = (const float*)d_in[20];
    P.qkv_w       = (const float*)d_in[21];
    P.attn_proj_w = (const float*)d_in[22];
    P.attn_proj_b = (const float*)d_in[23];
    P.ln2_g       = (const float*)d_in[24];
    P.ln2_b       = (const float*)d_in[25];
    P.mlp_w1      = (const float*)d_in[26];
    P.mlp_b1      = (const float*)d_in[27];
    P.mlp_w2      = (const float*)d_in[28];
    P.mlp_b2      = (const float*)d_in[29];
    P.wws         = (const u16*)d_ws;
    P.out         = (float*)d_out;
    static int smem_set = 0;
    if (!smem_set) {
        hipFuncSetAttribute(reinterpret_cast<const void*>(fused_block),
                            hipFuncAttributeMaxDynamicSharedMemorySize, SMEM_BYTES);
        smem_set = 1;
    }
    hipLaunchKernelGGL(prepack, dim3(712), dim3(256), 0, stream, P);
    hipLaunchKernelGGL(fused_block, dim3(2048), dim3(NTHR), SMEM_BYTES, stream, P);
}